// Round 2
// baseline (1144.373 us; speedup 1.0000x reference)
//
#include <hip/hip_runtime.h>
#include <math.h>

#define DIM   1024
#define HEADS 16
#define HDIM  64
#define FFDIM 4096
#define MROWS 4096   // B*T = 2*2048
#define SEQ   2048
#define QKVS  3072   // fused q|k|v row stride

typedef _Float16 f16x8 __attribute__((ext_vector_type(8)));
typedef _Float16 f16x4 __attribute__((ext_vector_type(4)));
typedef float    f32x4 __attribute__((ext_vector_type(4)));

// global -> LDS direct load, 16B per lane. LDS dest must be wave-uniform;
// hardware writes lane i at ldsbase + i*16B. Global src is per-lane.
#define GLOAD_LDS16(g, l) __builtin_amdgcn_global_load_lds(                 \
    (const __attribute__((address_space(1))) void*)(g),                     \
    (__attribute__((address_space(3))) void*)(l), 16, 0, 0)

__device__ __forceinline__ float gelu_exact(float x) {
    return 0.5f * x * (1.0f + erff(x * 0.70710678118654752f));
}

// ---------------------------------------------------------------------------
// LayerNorm: one 256-thread block per row of 1024 floats. fp16 output
// (feeds MFMA GEMMs as the A operand).
// ---------------------------------------------------------------------------
__global__ __launch_bounds__(256) void ln_kernel(
    const float* __restrict__ x, const float* __restrict__ g,
    const float* __restrict__ b, _Float16* __restrict__ out)
{
    const int row = blockIdx.x;
    const int t   = threadIdx.x;
    const float4* xr = reinterpret_cast<const float4*>(x + (size_t)row * DIM);
    float4 v = xr[t];
    float s  = v.x + v.y + v.z + v.w;
    float ss = v.x*v.x + v.y*v.y + v.z*v.z + v.w*v.w;
    #pragma unroll
    for (int off = 32; off; off >>= 1) {
        s  += __shfl_down(s,  off);
        ss += __shfl_down(ss, off);
    }
    __shared__ float red[8];
    const int wave = t >> 6, lane = t & 63;
    if (lane == 0) { red[wave] = s; red[4 + wave] = ss; }
    __syncthreads();
    if (t == 0) {
        float S  = red[0] + red[1] + red[2] + red[3];
        float SS = red[4] + red[5] + red[6] + red[7];
        float mu  = S * (1.0f / DIM);
        float var = SS * (1.0f / DIM) - mu * mu;
        red[0] = mu;
        red[1] = rsqrtf(var + 1e-5f);
    }
    __syncthreads();
    const float mu = red[0], inv = red[1];
    const float4 gv = reinterpret_cast<const float4*>(g)[t];
    const float4 bv = reinterpret_cast<const float4*>(b)[t];
    f16x4 o;
    o[0] = (_Float16)((v.x - mu) * inv * gv.x + bv.x);
    o[1] = (_Float16)((v.y - mu) * inv * gv.y + bv.y);
    o[2] = (_Float16)((v.z - mu) * inv * gv.z + bv.z);
    o[3] = (_Float16)((v.w - mu) * inv * gv.w + bv.w);
    *reinterpret_cast<f16x4*>(out + (size_t)row * DIM + t * 4) = o;
}

// concat bq|bk|bv -> bqkv[3072]
__global__ void concat3(const float* __restrict__ a, const float* __restrict__ b,
                        const float* __restrict__ c, float* __restrict__ dst)
{
    const int i = blockIdx.x * 256 + threadIdx.x;   // 0..3071
    if (i < 1024)      dst[i] = a[i];
    else if (i < 2048) dst[i] = b[i - 1024];
    else               dst[i] = c[i - 2048];
}

// ---------------------------------------------------------------------------
// Transpose + fp32->fp16 convert: src[R][C] f32 -> dst[dstOff + c][r] f16
// (dst row length = R). 32x32 LDS tiles, coalesced both sides.
// ---------------------------------------------------------------------------
__global__ __launch_bounds__(256) void transpose_cvt(
    const float* __restrict__ src, _Float16* __restrict__ dst,
    int R, int C, int dstOff)
{
    __shared__ float t[32][33];
    const int c0 = blockIdx.x * 32, r0 = blockIdx.y * 32;
    const int tx = threadIdx.x & 31, ty = (threadIdx.x >> 5) * 4;
    #pragma unroll
    for (int i = 0; i < 4; ++i)
        t[ty + i][tx] = src[(size_t)(r0 + ty + i) * C + c0 + tx];
    __syncthreads();
    #pragma unroll
    for (int i = 0; i < 4; ++i)
        dst[(size_t)(dstOff + c0 + ty + i) * R + r0 + tx] = (_Float16)t[tx][ty + i];
}

// ---------------------------------------------------------------------------
// fp16 MFMA GEMM (m97 structure): C[M,N] = epi(A[M,K] @ Bt[N,K]^T + bias)
// 128x128 tile, BK=32, 256 threads = 4 waves (2x2 of 64x64), 4x4 frags/wave,
// mfma_f32_16x16x32_f16, global_load_lds width-16 staging, fp32 accumulate.
// EPI: 0 = +bias -> f32 ; 1 = +bias+res -> f32 ; 2 = gelu(+bias) -> f16
// M,N multiples of 128; K multiple of 32.
// ---------------------------------------------------------------------------
template<int EPI>
__global__ __launch_bounds__(256) void gemm_mfma(
    const _Float16* __restrict__ A,   // [M][K]
    const _Float16* __restrict__ Bt,  // [N][K]  (W^T)
    const float* __restrict__ bias,   // [N]
    const float* __restrict__ res,    // [M][N] (EPI 1)
    float* __restrict__ Cf,           // f32 out (EPI 0,1)
    _Float16* __restrict__ Ch,        // f16 out (EPI 2)
    int M, int N, int K)
{
    __shared__ __attribute__((aligned(16))) _Float16 As[128 * 32];
    __shared__ __attribute__((aligned(16))) _Float16 Bs[128 * 32];

    const int tid  = threadIdx.x;
    const int wave = tid >> 6;
    const int lane = tid & 63;
    const int bm = blockIdx.y * 128;
    const int bn = blockIdx.x * 128;
    const int wr = wave >> 1, wc = wave & 1;     // 2x2 wave grid, 64x64 each

    // staging: chunk = 16 rows x 32 k = 1KB = one gload_lds. wave w owns
    // chunks {2w, 2w+1} of A and of Bt. lane i -> row i>>2, k-chunk (i&3)*8.
    const int c0   = wave * 2;
    const int srow = lane >> 2;
    const int skc  = lane & 3;
    const _Float16* Ag = A  + (size_t)(bm + c0 * 16 + srow) * K + skc * 8;
    const _Float16* Bg = Bt + (size_t)(bn + c0 * 16 + srow) * K + skc * 8;
    _Float16* Al = As + c0 * 512;   // chunk = 512 elements
    _Float16* Bl = Bs + c0 * 512;

    f32x4 acc[4][4] = {};

    const int fr = lane & 15;          // frag row (A) / frag col-as-row (Bt)
    const int fk = (lane >> 4) * 8;    // frag k offset

    for (int k0 = 0; k0 < K; k0 += 32) {
        __syncthreads();
        GLOAD_LDS16(Ag + k0,                  Al);
        GLOAD_LDS16(Ag + k0 + 16 * (size_t)K, Al + 512);
        GLOAD_LDS16(Bg + k0,                  Bl);
        GLOAD_LDS16(Bg + k0 + 16 * (size_t)K, Bl + 512);
        __syncthreads();   // drains vmcnt before any ds_read

        f16x8 af[4], bfr[4];
        #pragma unroll
        for (int m = 0; m < 4; ++m)
            af[m] = *reinterpret_cast<const f16x8*>(As + (wr * 64 + m * 16 + fr) * 32 + fk);
        #pragma unroll
        for (int n = 0; n < 4; ++n)
            bfr[n] = *reinterpret_cast<const f16x8*>(Bs + (wc * 64 + n * 16 + fr) * 32 + fk);
        #pragma unroll
        for (int m = 0; m < 4; ++m)
            #pragma unroll
            for (int n = 0; n < 4; ++n)
                acc[m][n] = __builtin_amdgcn_mfma_f32_16x16x32_f16(
                    af[m], bfr[n], acc[m][n], 0, 0, 0);
    }

    // epilogue. C/D layout: col = lane&15, row = (lane>>4)*4 + j  [HW-verified]
    const int fg = lane >> 4;
    #pragma unroll
    for (int m = 0; m < 4; ++m) {
        const int row0 = bm + wr * 64 + m * 16 + fg * 4;
        #pragma unroll
        for (int n = 0; n < 4; ++n) {
            const int col = bn + wc * 64 + n * 16 + fr;
            const float bv = bias[col];
            #pragma unroll
            for (int j = 0; j < 4; ++j) {
                const size_t idx = (size_t)(row0 + j) * N + col;
                float v = acc[m][n][j] + bv;
                if constexpr (EPI == 2) {
                    Ch[idx] = (_Float16)gelu_exact(v);
                } else {
                    if constexpr (EPI == 1) v += res[idx];
                    Cf[idx] = v;
                }
            }
        }
    }
}

// ---------------------------------------------------------------------------
// Flash-style attention, fp32 math. Reads fused QKV [MROWS][3072] f32
// (q: cols 0..1023, k: 1024..2047, v: 2048..3071; head h at h*64 within each).
// Writes attn out as f16 [MROWS][1024]. grid = (SEQ/64, HEADS, B), 256 thr.
// ---------------------------------------------------------------------------
__global__ __launch_bounds__(256) void attn_kernel(
    const float* __restrict__ QKV, _Float16* __restrict__ O)
{
    const int qt = blockIdx.x, h = blockIdx.y, b = blockIdx.z;
    __shared__ float Qs[64][68];
    __shared__ float Ks[64][68];
    __shared__ float Vs[64][68];
    __shared__ float Ss[64][68];

    const int tid = threadIdx.x;
    const int tr  = tid >> 4;   // rows tr*4..+3
    const int tc  = tid & 15;   // cols tc*4..+3

    const size_t qoff = (size_t)h * HDIM;
    const size_t koff = 1024 + qoff;
    const size_t voff = 2048 + qoff;

    // load Q tile, pre-scaled by 1/sqrt(64)
    {
        const size_t rowbase = (size_t)b * SEQ + (size_t)qt * 64;
        #pragma unroll
        for (int rep = 0; rep < 4; ++rep) {
            const int f   = tid + rep * 256;
            const int row = f >> 4, c4 = f & 15;
            float4 qv = *reinterpret_cast<const float4*>(
                QKV + (rowbase + row) * QKVS + qoff + c4 * 4);
            qv.x *= 0.125f; qv.y *= 0.125f; qv.z *= 0.125f; qv.w *= 0.125f;
            *reinterpret_cast<float4*>(&Qs[row][c4 * 4]) = qv;
        }
    }

    float m[4], l[4], o[4][4];
    #pragma unroll
    for (int i = 0; i < 4; ++i) {
        m[i] = -INFINITY; l[i] = 0.0f;
        #pragma unroll
        for (int j = 0; j < 4; ++j) o[i][j] = 0.0f;
    }

    for (int kt = 0; kt < SEQ / 64; ++kt) {
        __syncthreads();
        {
            const size_t rowbase = (size_t)b * SEQ + (size_t)kt * 64;
            #pragma unroll
            for (int rep = 0; rep < 4; ++rep) {
                const int f   = tid + rep * 256;
                const int row = f >> 4, c4 = f & 15;
                *reinterpret_cast<float4*>(&Ks[row][c4 * 4]) =
                    *reinterpret_cast<const float4*>(QKV + (rowbase + row) * QKVS + koff + c4 * 4);
                *reinterpret_cast<float4*>(&Vs[row][c4 * 4]) =
                    *reinterpret_cast<const float4*>(QKV + (rowbase + row) * QKVS + voff + c4 * 4);
            }
        }
        __syncthreads();

        float s[4][4];
        #pragma unroll
        for (int i = 0; i < 4; ++i)
            #pragma unroll
            for (int j = 0; j < 4; ++j) s[i][j] = 0.0f;
        #pragma unroll
        for (int k4 = 0; k4 < 16; ++k4) {
            float4 qv[4], kv[4];
            #pragma unroll
            for (int i = 0; i < 4; ++i)
                qv[i] = *reinterpret_cast<const float4*>(&Qs[tr * 4 + i][k4 * 4]);
            #pragma unroll
            for (int j = 0; j < 4; ++j)
                kv[j] = *reinterpret_cast<const float4*>(&Ks[tc * 4 + j][k4 * 4]);
            #pragma unroll
            for (int i = 0; i < 4; ++i)
                #pragma unroll
                for (int j = 0; j < 4; ++j) {
                    s[i][j] = fmaf(qv[i].x, kv[j].x, s[i][j]);
                    s[i][j] = fmaf(qv[i].y, kv[j].y, s[i][j]);
                    s[i][j] = fmaf(qv[i].z, kv[j].z, s[i][j]);
                    s[i][j] = fmaf(qv[i].w, kv[j].w, s[i][j]);
                }
        }

        #pragma unroll
        for (int i = 0; i < 4; ++i) {
            float mt = fmaxf(fmaxf(s[i][0], s[i][1]), fmaxf(s[i][2], s[i][3]));
            #pragma unroll
            for (int off = 1; off < 16; off <<= 1)
                mt = fmaxf(mt, __shfl_xor(mt, off));
            const float mnew  = fmaxf(m[i], mt);
            const float alpha = __expf(m[i] - mnew);
            float rs = 0.0f;
            #pragma unroll
            for (int j = 0; j < 4; ++j) {
                const float p = __expf(s[i][j] - mnew);
                s[i][j] = p;
                rs += p;
            }
            #pragma unroll
            for (int off = 1; off < 16; off <<= 1)
                rs += __shfl_xor(rs, off);
            l[i] = l[i] * alpha + rs;
            m[i] = mnew;
            #pragma unroll
            for (int j = 0; j < 4; ++j) o[i][j] *= alpha;
            #pragma unroll
            for (int j = 0; j < 4; ++j) Ss[tr * 4 + i][tc * 4 + j] = s[i][j];
        }
        __syncthreads();

        #pragma unroll
        for (int k4 = 0; k4 < 16; ++k4) {
            float4 pv[4];
            #pragma unroll
            for (int i = 0; i < 4; ++i)
                pv[i] = *reinterpret_cast<const float4*>(&Ss[tr * 4 + i][k4 * 4]);
            float4 vv[4];
            #pragma unroll
            for (int kk = 0; kk < 4; ++kk)
                vv[kk] = *reinterpret_cast<const float4*>(&Vs[k4 * 4 + kk][tc * 4]);
            #pragma unroll
            for (int i = 0; i < 4; ++i) {
                o[i][0] = fmaf(pv[i].x, vv[0].x, o[i][0]);
                o[i][1] = fmaf(pv[i].x, vv[0].y, o[i][1]);
                o[i][2] = fmaf(pv[i].x, vv[0].z, o[i][2]);
                o[i][3] = fmaf(pv[i].x, vv[0].w, o[i][3]);
                o[i][0] = fmaf(pv[i].y, vv[1].x, o[i][0]);
                o[i][1] = fmaf(pv[i].y, vv[1].y, o[i][1]);
                o[i][2] = fmaf(pv[i].y, vv[1].z, o[i][2]);
                o[i][3] = fmaf(pv[i].y, vv[1].w, o[i][3]);
                o[i][0] = fmaf(pv[i].z, vv[2].x, o[i][0]);
                o[i][1] = fmaf(pv[i].z, vv[2].y, o[i][1]);
                o[i][2] = fmaf(pv[i].z, vv[2].z, o[i][2]);
                o[i][3] = fmaf(pv[i].z, vv[2].w, o[i][3]);
                o[i][0] = fmaf(pv[i].w, vv[3].x, o[i][0]);
                o[i][1] = fmaf(pv[i].w, vv[3].y, o[i][1]);
                o[i][2] = fmaf(pv[i].w, vv[3].z, o[i][2]);
                o[i][3] = fmaf(pv[i].w, vv[3].w, o[i][3]);
            }
        }
    }

    const size_t rowbase = (size_t)b * SEQ + (size_t)qt * 64;
    #pragma unroll
    for (int i = 0; i < 4; ++i) {
        const float inv = 1.0f / l[i];
        f16x4 v;
        v[0] = (_Float16)(o[i][0] * inv);
        v[1] = (_Float16)(o[i][1] * inv);
        v[2] = (_Float16)(o[i][2] * inv);
        v[3] = (_Float16)(o[i][3] * inv);
        *reinterpret_cast<f16x4*>(
            O + (rowbase + tr * 4 + i) * DIM + qoff + tc * 4) = v;
    }
}

// ---------------------------------------------------------------------------
extern "C" void kernel_launch(void* const* d_in, const int* in_sizes, int n_in,
                              void* d_out, int out_size, void* d_ws, size_t ws_size,
                              hipStream_t stream)
{
    const float* x   = (const float*)d_in[0];
    const float* wq  = (const float*)d_in[1];
    const float* bq  = (const float*)d_in[2];
    const float* wk  = (const float*)d_in[3];
    const float* bk  = (const float*)d_in[4];
    const float* wv  = (const float*)d_in[5];
    const float* bv  = (const float*)d_in[6];
    const float* wo  = (const float*)d_in[7];
    const float* bo  = (const float*)d_in[8];
    const float* w1  = (const float*)d_in[9];
    const float* b1  = (const float*)d_in[10];
    const float* w2  = (const float*)d_in[11];
    const float* b2  = (const float*)d_in[12];
    const float* g1  = (const float*)d_in[13];
    const float* be1 = (const float*)d_in[14];
    const float* g2  = (const float*)d_in[15];
    const float* be2 = (const float*)d_in[16];
    float* out = (float*)d_out;

    // workspace layout (bytes), peak ~72 MB:
    //   [0,8M)    Wt      : per-GEMM transposed f16 weights (max 4M elems)
    //   [8M,16M)  normed  : f16 [4096][1024] (LN1 out, later LN2 out)
    //   [16M,64M) qkv     : f32 [4096][3072]  (reused as `mid` f16 after attn)
    //   [64M,72M) attno   : f16 [4096][1024]
    //   [72M,..)  bqkv    : f32 [3072]
    char* wsb = (char*)d_ws;
    _Float16* Wt     = (_Float16*)(wsb);
    _Float16* normed = (_Float16*)(wsb + ((size_t)8  << 20));
    float*    qkv    = (float*)   (wsb + ((size_t)16 << 20));
    _Float16* mid    = (_Float16*)(wsb + ((size_t)16 << 20));
    _Float16* attno  = (_Float16*)(wsb + ((size_t)64 << 20));
    float*    bqkv   = (float*)   (wsb + ((size_t)72 << 20));

    // 1. LN1 (f16 out)
    ln_kernel<<<MROWS, 256, 0, stream>>>(x, g1, be1, normed);
    // 2. fused QKV: Wt = [wq|wk|wv]^T  (rows 0..1023 | 1024..2047 | 2048..3071)
    concat3<<<12, 256, 0, stream>>>(bq, bk, bv, bqkv);
    transpose_cvt<<<dim3(32, 32), 256, 0, stream>>>(wq, Wt, 1024, 1024, 0);
    transpose_cvt<<<dim3(32, 32), 256, 0, stream>>>(wk, Wt, 1024, 1024, 1024);
    transpose_cvt<<<dim3(32, 32), 256, 0, stream>>>(wv, Wt, 1024, 1024, 2048);
    gemm_mfma<0><<<dim3(QKVS / 128, MROWS / 128), 256, 0, stream>>>(
        normed, Wt, bqkv, nullptr, qkv, nullptr, MROWS, QKVS, DIM);
    // 3. attention (f32 math, f16 out)
    attn_kernel<<<dim3(SEQ / 64, HEADS, 2), 256, 0, stream>>>(qkv, attno);
    // 4. x2 = x + attno @ wo + bo -> d_out (f32)
    transpose_cvt<<<dim3(32, 32), 256, 0, stream>>>(wo, Wt, 1024, 1024, 0);
    gemm_mfma<1><<<dim3(DIM / 128, MROWS / 128), 256, 0, stream>>>(
        attno, Wt, bo, x, out, nullptr, MROWS, DIM, DIM);
    // 5. LN2 (f16 out)
    ln_kernel<<<MROWS, 256, 0, stream>>>(out, g2, be2, normed);
    // 6. mid = gelu(h @ w1 + b1)  (f16)
    transpose_cvt<<<dim3(128, 32), 256, 0, stream>>>(w1, Wt, 1024, 4096, 0);
    gemm_mfma<2><<<dim3(FFDIM / 128, MROWS / 128), 256, 0, stream>>>(
        normed, Wt, b1, nullptr, nullptr, mid, MROWS, FFDIM, DIM);
    // 7. out = x2 + mid @ w2 + b2  (in-place residual, thread-local RMW)
    transpose_cvt<<<dim3(32, 128), 256, 0, stream>>>(w2, Wt, 4096, 1024, 0);
    gemm_mfma<1><<<dim3(DIM / 128, MROWS / 128), 256, 0, stream>>>(
        mid, Wt, b2, out, out, nullptr, MROWS, DIM, FFDIM);
}

// Round 3
// 475.565 us; speedup vs baseline: 2.4063x; 2.4063x over previous
//
#include <hip/hip_runtime.h>
#include <math.h>

#define DIM   1024
#define HEADS 16
#define HDIM  64
#define FFDIM 4096
#define MROWS 4096   // B*T = 2*2048
#define SEQ   2048
#define QKVS  3072   // fused q|k|v width
// 0.125 (1/sqrt(64)) * log2(e): folds softmax scale AND exp->exp2 into Q
#define SCALE_Q 0.1803368801111204f

typedef _Float16 f16x8 __attribute__((ext_vector_type(8)));
typedef _Float16 f16x4 __attribute__((ext_vector_type(4)));
typedef float    f32x4 __attribute__((ext_vector_type(4)));

#define GLOAD_LDS16(g, l) __builtin_amdgcn_global_load_lds(                 \
    (const __attribute__((address_space(1))) void*)(g),                     \
    (__attribute__((address_space(3))) void*)(l), 16, 0, 0)

__device__ __forceinline__ float gelu_exact(float x) {
    return 0.5f * x * (1.0f + erff(x * 0.70710678118654752f));
}

// pack two f32 -> one dword of 2 f16 (RNE via scalar casts)
__device__ __forceinline__ int pk2(float a, float b) {
    union { _Float16 h[2]; int i; } u;
    u.h[0] = (_Float16)a; u.h[1] = (_Float16)b;
    return u.i;
}

// ---------------------------------------------------------------------------
// LayerNorm: one 256-thread block per row of 1024 floats. fp16 output.
// ---------------------------------------------------------------------------
__global__ __launch_bounds__(256) void ln_kernel(
    const float* __restrict__ x, const float* __restrict__ g,
    const float* __restrict__ b, _Float16* __restrict__ out)
{
    const int row = blockIdx.x;
    const int t   = threadIdx.x;
    const float4* xr = reinterpret_cast<const float4*>(x + (size_t)row * DIM);
    float4 v = xr[t];
    float s  = v.x + v.y + v.z + v.w;
    float ss = v.x*v.x + v.y*v.y + v.z*v.z + v.w*v.w;
    #pragma unroll
    for (int off = 32; off; off >>= 1) {
        s  += __shfl_down(s,  off);
        ss += __shfl_down(ss, off);
    }
    __shared__ float red[8];
    const int wave = t >> 6, lane = t & 63;
    if (lane == 0) { red[wave] = s; red[4 + wave] = ss; }
    __syncthreads();
    if (t == 0) {
        float S  = red[0] + red[1] + red[2] + red[3];
        float SS = red[4] + red[5] + red[6] + red[7];
        float mu  = S * (1.0f / DIM);
        float var = SS * (1.0f / DIM) - mu * mu;
        red[0] = mu;
        red[1] = rsqrtf(var + 1e-5f);
    }
    __syncthreads();
    const float mu = red[0], inv = red[1];
    const float4 gv = reinterpret_cast<const float4*>(g)[t];
    const float4 bv = reinterpret_cast<const float4*>(b)[t];
    f16x4 o;
    o[0] = (_Float16)((v.x - mu) * inv * gv.x + bv.x);
    o[1] = (_Float16)((v.y - mu) * inv * gv.y + bv.y);
    o[2] = (_Float16)((v.z - mu) * inv * gv.z + bv.z);
    o[3] = (_Float16)((v.w - mu) * inv * gv.w + bv.w);
    *reinterpret_cast<f16x4*>(out + (size_t)row * DIM + t * 4) = o;
}

// concat bq|bk|bv -> bqkv[3072]
__global__ void concat3(const float* __restrict__ a, const float* __restrict__ b,
                        const float* __restrict__ c, float* __restrict__ dst)
{
    const int i = blockIdx.x * 256 + threadIdx.x;
    if (i < 1024)      dst[i] = a[i];
    else if (i < 2048) dst[i] = b[i - 1024];
    else               dst[i] = c[i - 2048];
}

// ---------------------------------------------------------------------------
// Transpose + fp32->fp16: src[R][C] f32 -> dst[dstOff + c][r] f16
// ---------------------------------------------------------------------------
__global__ __launch_bounds__(256) void transpose_cvt(
    const float* __restrict__ src, _Float16* __restrict__ dst,
    int R, int C, int dstOff)
{
    __shared__ float t[32][33];
    const int c0 = blockIdx.x * 32, r0 = blockIdx.y * 32;
    const int tx = threadIdx.x & 31, ty = (threadIdx.x >> 5) * 4;
    #pragma unroll
    for (int i = 0; i < 4; ++i)
        t[ty + i][tx] = src[(size_t)(r0 + ty + i) * C + c0 + tx];
    __syncthreads();
    #pragma unroll
    for (int i = 0; i < 4; ++i)
        dst[(size_t)(dstOff + c0 + ty + i) * R + r0 + tx] = (_Float16)t[tx][ty + i];
}

// ---------------------------------------------------------------------------
// fp16 MFMA GEMM (m97 structure): C = epi(A[M,K] @ Bt[N,K]^T + bias)
// EPI: 1 = +bias+res -> f32 ; 2 = gelu(+bias) -> f16 ;
//      3 = QKV scatter: q*SCALE_Q -> Qh[bh][t][64], k -> Kh[bh][t][64],
//          v -> Vtp[bh][64][T] (transposed, f16x4-packed along t)
// ---------------------------------------------------------------------------
template<int EPI>
__global__ __launch_bounds__(256) void gemm_mfma(
    const _Float16* __restrict__ A,   // [M][K]
    const _Float16* __restrict__ Bt,  // [N][K]
    const float* __restrict__ bias,   // [N]
    const float* __restrict__ res,    // [M][N] (EPI 1)
    float* __restrict__ Cf,           // f32 out (EPI 1)
    _Float16* __restrict__ Ch,        // f16 out (EPI 2)
    _Float16* __restrict__ Qh, _Float16* __restrict__ Kh,
    _Float16* __restrict__ Vtp,       // EPI 3 targets
    int M, int N, int K)
{
    __shared__ __attribute__((aligned(16))) _Float16 As[128 * 32];
    __shared__ __attribute__((aligned(16))) _Float16 Bs[128 * 32];

    const int tid  = threadIdx.x;
    const int wave = tid >> 6;
    const int lane = tid & 63;
    const int bm = blockIdx.y * 128;
    const int bn = blockIdx.x * 128;
    const int wr = wave >> 1, wc = wave & 1;

    const int c0   = wave * 2;
    const int srow = lane >> 2;
    const int skc  = lane & 3;
    const _Float16* Ag = A  + (size_t)(bm + c0 * 16 + srow) * K + skc * 8;
    const _Float16* Bg = Bt + (size_t)(bn + c0 * 16 + srow) * K + skc * 8;
    _Float16* Al = As + c0 * 512;
    _Float16* Bl = Bs + c0 * 512;

    f32x4 acc[4][4] = {};

    const int fr = lane & 15;
    const int fk = (lane >> 4) * 8;

    for (int k0 = 0; k0 < K; k0 += 32) {
        __syncthreads();
        GLOAD_LDS16(Ag + k0,                  Al);
        GLOAD_LDS16(Ag + k0 + 16 * (size_t)K, Al + 512);
        GLOAD_LDS16(Bg + k0,                  Bl);
        GLOAD_LDS16(Bg + k0 + 16 * (size_t)K, Bl + 512);
        __syncthreads();

        f16x8 af[4], bfr[4];
        #pragma unroll
        for (int m = 0; m < 4; ++m)
            af[m] = *reinterpret_cast<const f16x8*>(As + (wr * 64 + m * 16 + fr) * 32 + fk);
        #pragma unroll
        for (int n = 0; n < 4; ++n)
            bfr[n] = *reinterpret_cast<const f16x8*>(Bs + (wc * 64 + n * 16 + fr) * 32 + fk);
        #pragma unroll
        for (int m = 0; m < 4; ++m)
            #pragma unroll
            for (int n = 0; n < 4; ++n)
                acc[m][n] = __builtin_amdgcn_mfma_f32_16x16x32_f16(
                    af[m], bfr[n], acc[m][n], 0, 0, 0);
    }

    // epilogue. C/D: col = lane&15 (=fr), row = (lane>>4)*4 + j
    const int fg = lane >> 4;
    #pragma unroll
    for (int m = 0; m < 4; ++m) {
        const int row0 = bm + wr * 64 + m * 16 + fg * 4;
        #pragma unroll
        for (int n = 0; n < 4; ++n) {
            const int col = bn + wc * 64 + n * 16 + fr;
            const float bv = bias[col];
            if constexpr (EPI == 3) {
                const int b  = row0 >> 11;          // rows of a frag share b
                const int t0 = row0 & 2047;
                const int sect = col >> 10;
                const int h = (col >> 6) & 15;
                const int d = col & 63;
                const size_t bh = (size_t)(b * 16 + h);
                if (sect == 0) {
                    #pragma unroll
                    for (int j = 0; j < 4; ++j)
                        Qh[(bh * 2048 + t0 + j) * 64 + d] =
                            (_Float16)((acc[m][n][j] + bv) * SCALE_Q);
                } else if (sect == 1) {
                    #pragma unroll
                    for (int j = 0; j < 4; ++j)
                        Kh[(bh * 2048 + t0 + j) * 64 + d] =
                            (_Float16)(acc[m][n][j] + bv);
                } else {
                    f16x4 pv;
                    #pragma unroll
                    for (int j = 0; j < 4; ++j)
                        pv[j] = (_Float16)(acc[m][n][j] + bv);
                    *reinterpret_cast<f16x4*>(Vtp + (bh * 64 + d) * 2048 + t0) = pv;
                }
            } else {
                #pragma unroll
                for (int j = 0; j < 4; ++j) {
                    const size_t idx = (size_t)(row0 + j) * N + col;
                    float v = acc[m][n][j] + bv;
                    if constexpr (EPI == 2) {
                        Ch[idx] = (_Float16)gelu_exact(v);
                    } else {
                        v += res[idx];
                        Cf[idx] = v;
                    }
                }
            }
        }
    }
}

// ---------------------------------------------------------------------------
// MFMA flash attention.
// Qh [bh][T][64] (pre-scaled by 0.125*log2e), Kh [bh][T][64], Vt [bh][64][T].
// Block = 256 thr (4 waves), one (b,h,qt): 64 q-rows; wave w owns 16 q.
// Per kt tile (64 keys): S^T = mfma(K, Q) -> softmax (log2 domain, per-lane
// col=q) -> P^T repacked to B-frags via ds_bpermute -> O^T += mfma(Vt, P^T).
// K/Vt tiles: XOR-swizzled (16B-chunk ^ row&7) via pre-swizzled global src,
// double-buffered, gload_lds-staged. LDS 32KB.
// ---------------------------------------------------------------------------
__global__ __launch_bounds__(256) void attn_mfma(
    const _Float16* __restrict__ Qh, const _Float16* __restrict__ Kh,
    const _Float16* __restrict__ Vt, _Float16* __restrict__ O)
{
    __shared__ __attribute__((aligned(16))) _Float16 Kbuf[2][4096];
    __shared__ __attribute__((aligned(16))) _Float16 Vbuf[2][4096];

    // XCD-friendly decode: fid%8 (XCD) picks a bh-group; all 32 qt of a bh
    // land on one XCD -> 2MB K/V working set per XCD L2.
    const int fid = blockIdx.x;
    const int qt  = (fid >> 3) & 31;
    const int bh  = (fid & 7) * 4 + (fid >> 8);

    const int tid  = threadIdx.x;
    const int w    = tid >> 6;
    const int lane = tid & 63;
    const int fr   = lane & 15;
    const int g    = lane >> 4;

    // staging: chunk c = 1KB = rows c*8..c*8+7. wave w owns chunks {w, w+4}.
    // linear LDS (row, ch') holds global chunk ch'^(row&7)  (G21 pattern).
    const int srow_lo = lane >> 3;                  // 0..7
    const int sc      = (lane & 7) ^ (srow_lo & 7); // pre-swizzled global chunk
    const int rowA = w * 8 + srow_lo;
    const int rowB = (w + 4) * 8 + srow_lo;
    const char* Kg = (const char*)(Kh + (size_t)bh * (2048 * 64));
    const char* Vg = (const char*)(Vt + (size_t)bh * (64 * 2048));

#define STAGE(nb, kt) do {                                                   \
    GLOAD_LDS16(Kg + ((size_t)(((kt) * 64 + rowA)) << 7) + (sc << 4),        \
                &Kbuf[nb][w * 512]);                                         \
    GLOAD_LDS16(Kg + ((size_t)(((kt) * 64 + rowB)) << 7) + (sc << 4),        \
                &Kbuf[nb][(w + 4) * 512]);                                   \
    GLOAD_LDS16(Vg + ((size_t)rowA << 12) + ((kt) << 7) + (sc << 4),         \
                &Vbuf[nb][w * 512]);                                         \
    GLOAD_LDS16(Vg + ((size_t)rowB << 12) + ((kt) << 7) + (sc << 4),         \
                &Vbuf[nb][(w + 4) * 512]);                                   \
} while (0)

    // persistent Q B-frags: lane(fr,g) holds Q[qrow=w*16+fr][s*32+8g..+7]
    const int qrow = qt * 64 + w * 16 + fr;
    const f16x8* Qp = reinterpret_cast<const f16x8*>(
        Qh + ((size_t)bh * 2048 + qrow) * 64);
    const f16x8 qf0 = Qp[g];
    const f16x8 qf1 = Qp[4 + g];

    // frag-read byte offsets within a tile row: ((4*ks+g)^(fr&7))*16
    const int fr7 = fr & 7;
    const int cs0 = ((g ^ fr7) << 4);
    const int cs1 = (((4 + g) ^ fr7) << 4);

    f32x4 o[4] = {};
    float mrun = -INFINITY, l = 0.0f;

    // bpermute indices (byte = lane*4): src lane = fr + 16*(2*(g&1) + hi4)
    const int idx0 = (fr + ((g & 1) << 5)) << 2;
    const int idx1 = idx0 + 64;
    const bool ghi = (g >= 2);

    STAGE(0, 0);
    __syncthreads();
    int cur = 0;

    for (int kt = 0; kt < 32; ++kt) {
        if (kt < 31) STAGE(cur ^ 1, kt + 1);

        // ---- S^T = K . Q^T  (D[m=k][n=q]) ----
        f32x4 sT[4] = {};
        {
            const char* Kb = (const char*)Kbuf[cur];
            #pragma unroll
            for (int mm = 0; mm < 4; ++mm) {
                const char* rb = Kb + ((mm * 16 + fr) << 7);
                f16x8 ka = *reinterpret_cast<const f16x8*>(rb + cs0);
                f16x8 kb = *reinterpret_cast<const f16x8*>(rb + cs1);
                sT[mm] = __builtin_amdgcn_mfma_f32_16x16x32_f16(ka, qf0, sT[mm], 0, 0, 0);
                sT[mm] = __builtin_amdgcn_mfma_f32_16x16x32_f16(kb, qf1, sT[mm], 0, 0, 0);
            }
        }

        // ---- online softmax (log2 domain); lane owns 16 k's of q=fr ----
        float pm = sT[0][0];
        #pragma unroll
        for (int mm = 0; mm < 4; ++mm)
            #pragma unroll
            for (int j = 0; j < 4; ++j) pm = fmaxf(pm, sT[mm][j]);
        pm = fmaxf(pm, __shfl_xor(pm, 16));
        pm = fmaxf(pm, __shfl_xor(pm, 32));
        const float mnew  = fmaxf(mrun, pm);
        const float alpha = exp2f(mrun - mnew);
        mrun = mnew;
        float rs = 0.0f;
        #pragma unroll
        for (int mm = 0; mm < 4; ++mm)
            #pragma unroll
            for (int j = 0; j < 4; ++j) {
                const float p = exp2f(sT[mm][j] - mnew);
                sT[mm][j] = p;
                rs += p;
            }
        rs += __shfl_xor(rs, 16);
        rs += __shfl_xor(rs, 32);
        l = l * alpha + rs;
        #pragma unroll
        for (int mm = 0; mm < 4; ++mm)
            #pragma unroll
            for (int j = 0; j < 4; ++j) o[mm][j] *= alpha;

        // ---- pack P to f16 pairs: pk[mm][pp] = (p[2pp], p[2pp+1]) ----
        int pk[4][2];
        #pragma unroll
        for (int mm = 0; mm < 4; ++mm) {
            pk[mm][0] = pk2(sT[mm][0], sT[mm][1]);
            pk[mm][1] = pk2(sT[mm][2], sT[mm][3]);
        }

        // ---- repack P^T -> PV B-frags (lane(fr,g): P[q=fr][32s+8g+j]) ----
        union BF { int i[4]; f16x8 h; } bf0, bf1;
        #pragma unroll
        for (int s = 0; s < 2; ++s) {
            union BF* bf = s ? &bf1 : &bf0;
            const int rA = 2 * s, rB = 2 * s + 1;   // mm_s = 2s + (g>>1)
            int a0 = __builtin_amdgcn_ds_bpermute(idx0, pk[rA][0]);
            int b0 = __builtin_amdgcn_ds_bpermute(idx0, pk[rB][0]);
            int a1 = __builtin_amdgcn_ds_bpermute(idx0, pk[rA][1]);
            int b1 = __builtin_amdgcn_ds_bpermute(idx0, pk[rB][1]);
            int a2 = __builtin_amdgcn_ds_bpermute(idx1, pk[rA][0]);
            int b2 = __builtin_amdgcn_ds_bpermute(idx1, pk[rB][0]);
            int a3 = __builtin_amdgcn_ds_bpermute(idx1, pk[rA][1]);
            int b3 = __builtin_amdgcn_ds_bpermute(idx1, pk[rB][1]);
            bf->i[0] = ghi ? b0 : a0;
            bf->i[1] = ghi ? b1 : a1;
            bf->i[2] = ghi ? b2 : a2;
            bf->i[3] = ghi ? b3 : a3;
        }

        // ---- O^T += Vt . P^T  (D[m=d][n=q]) ----
        {
            const char* Vb = (const char*)Vbuf[cur];
            #pragma unroll
            for (int mm = 0; mm < 4; ++mm) {
                const char* rb = Vb + ((mm * 16 + fr) << 7);
                f16x8 va = *reinterpret_cast<const f16x8*>(rb + cs0);
                f16x8 vb = *reinterpret_cast<const f16x8*>(rb + cs1);
                o[mm] = __builtin_amdgcn_mfma_f32_16x16x32_f16(va, bf0.h, o[mm], 0, 0, 0);
                o[mm] = __builtin_amdgcn_mfma_f32_16x16x32_f16(vb, bf1.h, o[mm], 0, 0, 0);
            }
        }

        __syncthreads();
        cur ^= 1;
    }
#undef STAGE

    // ---- epilogue: lane holds O[q = qt*64+w*16+fr][d = mm*16+4g+j] ----
    const float linv = 1.0f / l;
    const int b = bh >> 4, h = bh & 15;
    _Float16* Op = O + (size_t)(b * 2048 + qt * 64 + w * 16 + fr) * DIM
                     + h * 64 + 4 * g;
    #pragma unroll
    for (int mm = 0; mm < 4; ++mm) {
        f16x4 st;
        #pragma unroll
        for (int j = 0; j < 4; ++j) st[j] = (_Float16)(o[mm][j] * linv);
        *reinterpret_cast<f16x4*>(Op + mm * 16) = st;
    }
}

// ---------------------------------------------------------------------------
extern "C" void kernel_launch(void* const* d_in, const int* in_sizes, int n_in,
                              void* d_out, int out_size, void* d_ws, size_t ws_size,
                              hipStream_t stream)
{
    const float* x   = (const float*)d_in[0];
    const float* wq  = (const float*)d_in[1];
    const float* bq  = (const float*)d_in[2];
    const float* wk  = (const float*)d_in[3];
    const float* bk  = (const float*)d_in[4];
    const float* wv  = (const float*)d_in[5];
    const float* bv  = (const float*)d_in[6];
    const float* wo  = (const float*)d_in[7];
    const float* bo  = (const float*)d_in[8];
    const float* w1  = (const float*)d_in[9];
    const float* b1  = (const float*)d_in[10];
    const float* w2  = (const float*)d_in[11];
    const float* b2  = (const float*)d_in[12];
    const float* g1  = (const float*)d_in[13];
    const float* be1 = (const float*)d_in[14];
    const float* g2  = (const float*)d_in[15];
    const float* be2 = (const float*)d_in[16];
    float* out = (float*)d_out;

    // ws layout (peak 48MB + 12KB):
    //  [0,8M)   Wt      f16 transposed weights (per-GEMM)
    //  [8,16M)  normed  f16 [4096][1024]
    //  [16,24M) Qh      f16 [32][2048][64]   \
    //  [24,32M) Kh      f16 [32][2048][64]    } mid f16 [4096][4096] reuses
    //  [32,40M) Vt      f16 [32][64][2048]    } [16M,48M) after attention
    //  [40,48M) attno   f16 [4096][1024]     /  (attno dead before FFN1)
    //  [48M,+12K) bqkv  f32 [3072]
    char* wsb = (char*)d_ws;
    _Float16* Wt     = (_Float16*)(wsb);
    _Float16* normed = (_Float16*)(wsb + ((size_t)8  << 20));
    _Float16* Qh     = (_Float16*)(wsb + ((size_t)16 << 20));
    _Float16* Kh     = (_Float16*)(wsb + ((size_t)24 << 20));
    _Float16* Vt     = (_Float16*)(wsb + ((size_t)32 << 20));
    _Float16* mid    = (_Float16*)(wsb + ((size_t)16 << 20));
    _Float16* attno  = (_Float16*)(wsb + ((size_t)40 << 20));
    float*    bqkv   = (float*)   (wsb + ((size_t)48 << 20));

    // 1. LN1
    ln_kernel<<<MROWS, 256, 0, stream>>>(x, g1, be1, normed);
    // 2. fused QKV -> scattered f16 Q/K/Vt layouts
    concat3<<<12, 256, 0, stream>>>(bq, bk, bv, bqkv);
    transpose_cvt<<<dim3(32, 32), 256, 0, stream>>>(wq, Wt, 1024, 1024, 0);
    transpose_cvt<<<dim3(32, 32), 256, 0, stream>>>(wk, Wt, 1024, 1024, 1024);
    transpose_cvt<<<dim3(32, 32), 256, 0, stream>>>(wv, Wt, 1024, 1024, 2048);
    gemm_mfma<3><<<dim3(QKVS / 128, MROWS / 128), 256, 0, stream>>>(
        normed, Wt, bqkv, nullptr, nullptr, nullptr, Qh, Kh, Vt,
        MROWS, QKVS, DIM);
    // 3. MFMA flash attention
    attn_mfma<<<1024, 256, 0, stream>>>(Qh, Kh, Vt, attno);
    // 4. x2 = x + attno @ wo + bo -> d_out (f32)
    transpose_cvt<<<dim3(32, 32), 256, 0, stream>>>(wo, Wt, 1024, 1024, 0);
    gemm_mfma<1><<<dim3(DIM / 128, MROWS / 128), 256, 0, stream>>>(
        attno, Wt, bo, x, out, nullptr, nullptr, nullptr, nullptr,
        MROWS, DIM, DIM);
    // 5. LN2
    ln_kernel<<<MROWS, 256, 0, stream>>>(out, g2, be2, normed);
    // 6. mid = gelu(h @ w1 + b1)  (f16)
    transpose_cvt<<<dim3(128, 32), 256, 0, stream>>>(w1, Wt, 1024, 4096, 0);
    gemm_mfma<2><<<dim3(FFDIM / 128, MROWS / 128), 256, 0, stream>>>(
        normed, Wt, b1, nullptr, nullptr, mid, nullptr, nullptr, nullptr,
        MROWS, FFDIM, DIM);
    // 7. out = x2 + mid @ w2 + b2  (in-place residual, same-thread RMW)
    transpose_cvt<<<dim3(32, 128), 256, 0, stream>>>(w2, Wt, 4096, 1024, 0);
    gemm_mfma<1><<<dim3(DIM / 128, MROWS / 128), 256, 0, stream>>>(
        mid, Wt, b2, out, out, nullptr, nullptr, nullptr, nullptr,
        MROWS, DIM, FFDIM);
}

// Round 4
// 457.303 us; speedup vs baseline: 2.5024x; 1.0399x over previous
//
#include <hip/hip_runtime.h>
#include <math.h>

#define DIM   1024
#define HEADS 16
#define HDIM  64
#define FFDIM 4096
#define MROWS 4096   // B*T = 2*2048
#define SEQ   2048
#define QKVS  3072   // fused q|k|v width
// 0.125 (1/sqrt(64)) * log2(e): folds softmax scale AND exp->exp2 into Q
#define SCALE_Q 0.1803368801111204f

typedef _Float16 f16x8 __attribute__((ext_vector_type(8)));
typedef _Float16 f16x4 __attribute__((ext_vector_type(4)));
typedef float    f32x4 __attribute__((ext_vector_type(4)));

#define GLOAD_LDS16(g, l) __builtin_amdgcn_global_load_lds(                 \
    (const __attribute__((address_space(1))) void*)(g),                     \
    (__attribute__((address_space(3))) void*)(l), 16, 0, 0)

__device__ __forceinline__ float gelu_exact(float x) {
    return 0.5f * x * (1.0f + erff(x * 0.70710678118654752f));
}

__device__ __forceinline__ int pk2(float a, float b) {
    union { _Float16 h[2]; int i; } u;
    u.h[0] = (_Float16)a; u.h[1] = (_Float16)b;
    return u.i;
}

// ---------------------------------------------------------------------------
// LayerNorm: one 256-thread block per row of 1024 floats. fp16 output.
// ---------------------------------------------------------------------------
__global__ __launch_bounds__(256) void ln_kernel(
    const float* __restrict__ x, const float* __restrict__ g,
    const float* __restrict__ b, _Float16* __restrict__ out)
{
    const int row = blockIdx.x;
    const int t   = threadIdx.x;
    const float4* xr = reinterpret_cast<const float4*>(x + (size_t)row * DIM);
    float4 v = xr[t];
    float s  = v.x + v.y + v.z + v.w;
    float ss = v.x*v.x + v.y*v.y + v.z*v.z + v.w*v.w;
    #pragma unroll
    for (int off = 32; off; off >>= 1) {
        s  += __shfl_down(s,  off);
        ss += __shfl_down(ss, off);
    }
    __shared__ float red[8];
    const int wave = t >> 6, lane = t & 63;
    if (lane == 0) { red[wave] = s; red[4 + wave] = ss; }
    __syncthreads();
    if (t == 0) {
        float S  = red[0] + red[1] + red[2] + red[3];
        float SS = red[4] + red[5] + red[6] + red[7];
        float mu  = S * (1.0f / DIM);
        float var = SS * (1.0f / DIM) - mu * mu;
        red[0] = mu;
        red[1] = rsqrtf(var + 1e-5f);
    }
    __syncthreads();
    const float mu = red[0], inv = red[1];
    const float4 gv = reinterpret_cast<const float4*>(g)[t];
    const float4 bv = reinterpret_cast<const float4*>(b)[t];
    f16x4 o;
    o[0] = (_Float16)((v.x - mu) * inv * gv.x + bv.x);
    o[1] = (_Float16)((v.y - mu) * inv * gv.y + bv.y);
    o[2] = (_Float16)((v.z - mu) * inv * gv.z + bv.z);
    o[3] = (_Float16)((v.w - mu) * inv * gv.w + bv.w);
    *reinterpret_cast<f16x4*>(out + (size_t)row * DIM + t * 4) = o;
}

// concat bq|bk|bv -> bqkv[3072]
__global__ void concat3(const float* __restrict__ a, const float* __restrict__ b,
                        const float* __restrict__ c, float* __restrict__ dst)
{
    const int i = blockIdx.x * 256 + threadIdx.x;
    if (i < 1024)      dst[i] = a[i];
    else if (i < 2048) dst[i] = b[i - 1024];
    else               dst[i] = c[i - 2048];
}

// ---------------------------------------------------------------------------
// Transpose + fp32->fp16: src[R][C] f32 -> dst[dstOff + c][r] f16
// ---------------------------------------------------------------------------
__global__ __launch_bounds__(256) void transpose_cvt(
    const float* __restrict__ src, _Float16* __restrict__ dst,
    int R, int C, int dstOff)
{
    __shared__ float t[32][33];
    const int c0 = blockIdx.x * 32, r0 = blockIdx.y * 32;
    const int tx = threadIdx.x & 31, ty = (threadIdx.x >> 5) * 4;
    #pragma unroll
    for (int i = 0; i < 4; ++i)
        t[ty + i][tx] = src[(size_t)(r0 + ty + i) * C + c0 + tx];
    __syncthreads();
    #pragma unroll
    for (int i = 0; i < 4; ++i)
        dst[(size_t)(dstOff + c0 + ty + i) * R + r0 + tx] = (_Float16)t[tx][ty + i];
}

// fused wq|wk|wv transpose (z picks source), all 1024x1024
__global__ __launch_bounds__(256) void transpose_cvt3(
    const float* __restrict__ s0, const float* __restrict__ s1,
    const float* __restrict__ s2, _Float16* __restrict__ dst)
{
    __shared__ float t[32][33];
    const float* src = blockIdx.z == 0 ? s0 : (blockIdx.z == 1 ? s1 : s2);
    const int dstOff = blockIdx.z * 1024;
    const int c0 = blockIdx.x * 32, r0 = blockIdx.y * 32;
    const int tx = threadIdx.x & 31, ty = (threadIdx.x >> 5) * 4;
    #pragma unroll
    for (int i = 0; i < 4; ++i)
        t[ty + i][tx] = src[(size_t)(r0 + ty + i) * 1024 + c0 + tx];
    __syncthreads();
    #pragma unroll
    for (int i = 0; i < 4; ++i)
        dst[(size_t)(dstOff + c0 + ty + i) * 1024 + r0 + tx] = (_Float16)t[tx][ty + i];
}

// ---------------------------------------------------------------------------
// fp16 MFMA GEMM: C = epi(A[M,K] @ Bt[N,K]^T + bias), tile BM x 128, BK=32,
// 4 waves (2x2), mfma_f32_16x16x32_f16, gload_lds staging, f32 accumulate.
// EPI 1: +bias+res -> f32 (direct store)
// EPI 2: gelu(+bias) -> f16 row-major (LDS-bounce coalesced store)
// EPI 3: QKV scatter via LDS-bounce: q*SCALE_Q -> Qh[bh][t][64],
//        k -> Kh[bh][t][64], v -> Vt[bh][64][T]
// ---------------------------------------------------------------------------
template<int EPI, int BM>
__global__ __launch_bounds__(256) void gemm_mfma(
    const _Float16* __restrict__ A,   // [M][K]
    const _Float16* __restrict__ Bt,  // [N][K]
    const float* __restrict__ bias,   // [N]
    const float* __restrict__ res,    // [M][N] (EPI 1)
    float* __restrict__ Cf,           // f32 out (EPI 1)
    _Float16* __restrict__ Ch,        // f16 out (EPI 2)
    _Float16* __restrict__ Qh, _Float16* __restrict__ Kh,
    _Float16* __restrict__ Vtp,       // EPI 3 targets
    int M, int N, int K)
{
    constexpr int MF  = BM / 32;   // m-frags per wave
    constexpr int ACH = BM / 64;   // A chunks staged per wave
    __shared__ __attribute__((aligned(16))) _Float16 SMEM[8192];  // 16 KB
    _Float16* As = SMEM;             // BM*32
    _Float16* Bs = SMEM + BM * 32;   // 128*32

    const int tid  = threadIdx.x;
    const int wave = tid >> 6;
    const int lane = tid & 63;
    const int bm = blockIdx.y * BM;
    const int bn = blockIdx.x * 128;
    const int wr = wave >> 1, wc = wave & 1;

    const int srow = lane >> 2;
    const int skc  = lane & 3;
    const _Float16* Ag = A  + (size_t)(bm + wave * ACH * 16 + srow) * K + skc * 8;
    const _Float16* Bg = Bt + (size_t)(bn + wave * 32 + srow) * K + skc * 8;
    _Float16* Al = As + wave * ACH * 512;
    _Float16* Bl = Bs + wave * 1024;

    f32x4 acc[MF][4] = {};

    const int fr = lane & 15;
    const int fk = (lane >> 4) * 8;

    for (int k0 = 0; k0 < K; k0 += 32) {
        __syncthreads();
        #pragma unroll
        for (int c = 0; c < ACH; ++c)
            GLOAD_LDS16(Ag + k0 + (size_t)c * 16 * K, Al + c * 512);
        GLOAD_LDS16(Bg + k0,                  Bl);
        GLOAD_LDS16(Bg + k0 + 16 * (size_t)K, Bl + 512);
        __syncthreads();

        f16x8 af[MF], bfr[4];
        #pragma unroll
        for (int m = 0; m < MF; ++m)
            af[m] = *reinterpret_cast<const f16x8*>(As + (wr * (BM/2) + m * 16 + fr) * 32 + fk);
        #pragma unroll
        for (int n = 0; n < 4; ++n)
            bfr[n] = *reinterpret_cast<const f16x8*>(Bs + (wc * 64 + n * 16 + fr) * 32 + fk);
        #pragma unroll
        for (int m = 0; m < MF; ++m)
            #pragma unroll
            for (int n = 0; n < 4; ++n)
                acc[m][n] = __builtin_amdgcn_mfma_f32_16x16x32_f16(
                    af[m], bfr[n], acc[m][n], 0, 0, 0);
    }

    // C/D frag: col = lane&15 (=fr), row = (lane>>4)*4 + j
    const int fg = lane >> 4;

    if constexpr (EPI == 1) {
        #pragma unroll
        for (int m = 0; m < MF; ++m) {
            const int row0 = bm + wr * (BM/2) + m * 16 + fg * 4;
            #pragma unroll
            for (int n = 0; n < 4; ++n) {
                const int col = bn + wc * 64 + n * 16 + fr;
                const float bv = bias[col];
                #pragma unroll
                for (int j = 0; j < 4; ++j) {
                    const size_t idx = (size_t)(row0 + j) * N + col;
                    Cf[idx] = acc[m][n][j] + bv + res[idx];
                }
            }
        }
        return;
    }

    // ---- LDS-bounce epilogue (EPI 2, 3): per-wave 32x64 f16 tiles ----
    // wtile rows r (t-dim), cols c (n-dim); 16B chunks XOR-swizzled by r&7.
    _Float16* wtile = SMEM + wave * 2048;

    // EPI3 geometry (block-uniform section; wave covers full d=0..63)
    const int sect = bn >> 10;                       // 0=q 1=k 2=v
    const int bidx = bm >> 11;                       // batch
    const int t0w  = (bm & 2047) + wr * (BM / 2);    // wave's t base
    const int hh   = ((bn & 1023) >> 6) + wc;
    const size_t bh = (size_t)(bidx * 16 + hh);

    #pragma unroll
    for (int pass = 0; pass < MF / 2; ++pass) {
        __syncthreads();   // staging LDS / previous pass reads complete
        #pragma unroll
        for (int mi = 0; mi < 2; ++mi) {
            const int mm = pass * 2 + mi;
            #pragma unroll
            for (int n = 0; n < 4; ++n) {
                const int cl = n * 16 + fr;
                const float bv = bias[bn + wc * 64 + cl];
                #pragma unroll
                for (int j = 0; j < 4; ++j) {
                    const int rl = mi * 16 + fg * 4 + j;
                    float v = acc[mm][n][j] + bv;
                    _Float16 hv;
                    if constexpr (EPI == 2) hv = (_Float16)gelu_exact(v);
                    else hv = (_Float16)(sect == 0 ? v * SCALE_Q : v);
                    wtile[rl * 64 + ((((cl >> 3) ^ (rl & 7))) << 3) + (cl & 7)] = hv;
                }
            }
        }
        __syncthreads();

        if constexpr (EPI == 2) {
            _Float16* dst = Ch + (size_t)(bm + wr * (BM/2) + pass * 32) * N
                               + bn + wc * 64;
            #pragma unroll
            for (int it = 0; it < 4; ++it) {
                const int rl = it * 8 + (lane >> 3);
                const int ch = lane & 7;
                f16x8 vv = *reinterpret_cast<const f16x8*>(
                    wtile + rl * 64 + ((ch ^ (rl & 7)) << 3));
                *reinterpret_cast<f16x8*>(dst + (size_t)rl * N + ch * 8) = vv;
            }
        } else {  // EPI == 3
            if (sect < 2) {
                _Float16* dst = (sect == 0 ? Qh : Kh)
                              + (bh * 2048 + t0w + pass * 32) * 64;
                #pragma unroll
                for (int it = 0; it < 4; ++it) {
                    const int rl = it * 8 + (lane >> 3);
                    const int ch = lane & 7;
                    f16x8 vv = *reinterpret_cast<const f16x8*>(
                        wtile + rl * 64 + ((ch ^ (rl & 7)) << 3));
                    *reinterpret_cast<f16x8*>(dst + (size_t)rl * 64 + ch * 8) = vv;
                }
            } else {
                // V: transpose read (column d, 8 t's) -> Vt[bh][d][T]
                _Float16* dst = Vtp + bh * (64 * 2048) + t0w + pass * 32;
                #pragma unroll
                for (int it = 0; it < 4; ++it) {
                    const int d   = it * 16 + (lane >> 2);
                    const int tch = lane & 3;
                    f16x8 vv;
                    #pragma unroll
                    for (int u = 0; u < 8; ++u) {
                        const int rl = tch * 8 + u;
                        vv[u] = wtile[rl * 64 + (((d >> 3) ^ (rl & 7)) << 3) + (d & 7)];
                    }
                    *reinterpret_cast<f16x8*>(dst + (size_t)d * 2048 + tch * 8) = vv;
                }
            }
        }
    }
}

// ---------------------------------------------------------------------------
// MFMA flash attention (unchanged structure + T13 defer-max).
// Qh [bh][T][64] (pre-scaled), Kh [bh][T][64], Vt [bh][64][T].
// ---------------------------------------------------------------------------
__global__ __launch_bounds__(256) void attn_mfma(
    const _Float16* __restrict__ Qh, const _Float16* __restrict__ Kh,
    const _Float16* __restrict__ Vt, _Float16* __restrict__ O)
{
    __shared__ __attribute__((aligned(16))) _Float16 Kbuf[2][4096];
    __shared__ __attribute__((aligned(16))) _Float16 Vbuf[2][4096];

    const int fid = blockIdx.x;
    const int qt  = (fid >> 3) & 31;
    const int bh  = (fid & 7) * 4 + (fid >> 8);

    const int tid  = threadIdx.x;
    const int w    = tid >> 6;
    const int lane = tid & 63;
    const int fr   = lane & 15;
    const int g    = lane >> 4;

    const int srow_lo = lane >> 3;
    const int sc      = (lane & 7) ^ (srow_lo & 7);
    const int rowA = w * 8 + srow_lo;
    const int rowB = (w + 4) * 8 + srow_lo;
    const char* Kg = (const char*)(Kh + (size_t)bh * (2048 * 64));
    const char* Vg = (const char*)(Vt + (size_t)bh * (64 * 2048));

#define STAGE(nb, kt) do {                                                   \
    GLOAD_LDS16(Kg + ((size_t)(((kt) * 64 + rowA)) << 7) + (sc << 4),        \
                &Kbuf[nb][w * 512]);                                         \
    GLOAD_LDS16(Kg + ((size_t)(((kt) * 64 + rowB)) << 7) + (sc << 4),        \
                &Kbuf[nb][(w + 4) * 512]);                                   \
    GLOAD_LDS16(Vg + ((size_t)rowA << 12) + ((kt) << 7) + (sc << 4),         \
                &Vbuf[nb][w * 512]);                                         \
    GLOAD_LDS16(Vg + ((size_t)rowB << 12) + ((kt) << 7) + (sc << 4),         \
                &Vbuf[nb][(w + 4) * 512]);                                   \
} while (0)

    const int qrow = qt * 64 + w * 16 + fr;
    const f16x8* Qp = reinterpret_cast<const f16x8*>(
        Qh + ((size_t)bh * 2048 + qrow) * 64);
    const f16x8 qf0 = Qp[g];
    const f16x8 qf1 = Qp[4 + g];

    const int fr7 = fr & 7;
    const int cs0 = ((g ^ fr7) << 4);
    const int cs1 = (((4 + g) ^ fr7) << 4);

    f32x4 o[4] = {};
    float mrun = -INFINITY, l = 0.0f;

    const int idx0 = (fr + ((g & 1) << 5)) << 2;
    const int idx1 = idx0 + 64;
    const bool ghi = (g >= 2);

    STAGE(0, 0);
    __syncthreads();
    int cur = 0;

    for (int kt = 0; kt < 32; ++kt) {
        if (kt < 31) STAGE(cur ^ 1, kt + 1);

        // ---- S^T = K . Q^T ----
        f32x4 sT[4] = {};
        {
            const char* Kb = (const char*)Kbuf[cur];
            #pragma unroll
            for (int mm = 0; mm < 4; ++mm) {
                const char* rb = Kb + ((mm * 16 + fr) << 7);
                f16x8 ka = *reinterpret_cast<const f16x8*>(rb + cs0);
                f16x8 kb = *reinterpret_cast<const f16x8*>(rb + cs1);
                sT[mm] = __builtin_amdgcn_mfma_f32_16x16x32_f16(ka, qf0, sT[mm], 0, 0, 0);
                sT[mm] = __builtin_amdgcn_mfma_f32_16x16x32_f16(kb, qf1, sT[mm], 0, 0, 0);
            }
        }

        // ---- online softmax (log2 domain) with defer-max (T13) ----
        float pm = sT[0][0];
        #pragma unroll
        for (int mm = 0; mm < 4; ++mm)
            #pragma unroll
            for (int j = 0; j < 4; ++j) pm = fmaxf(pm, sT[mm][j]);
        pm = fmaxf(pm, __shfl_xor(pm, 16));
        pm = fmaxf(pm, __shfl_xor(pm, 32));
        if (!__all(pm - mrun <= 8.0f)) {
            const float mnew  = fmaxf(mrun, pm);
            const float alpha = exp2f(mrun - mnew);
            mrun = mnew;
            l *= alpha;
            #pragma unroll
            for (int mm = 0; mm < 4; ++mm)
                #pragma unroll
                for (int j = 0; j < 4; ++j) o[mm][j] *= alpha;
        }
        float rs = 0.0f;
        #pragma unroll
        for (int mm = 0; mm < 4; ++mm)
            #pragma unroll
            for (int j = 0; j < 4; ++j) {
                const float p = exp2f(sT[mm][j] - mrun);
                sT[mm][j] = p;
                rs += p;
            }
        rs += __shfl_xor(rs, 16);
        rs += __shfl_xor(rs, 32);
        l += rs;

        // ---- pack P to f16 pairs ----
        int pk[4][2];
        #pragma unroll
        for (int mm = 0; mm < 4; ++mm) {
            pk[mm][0] = pk2(sT[mm][0], sT[mm][1]);
            pk[mm][1] = pk2(sT[mm][2], sT[mm][3]);
        }

        // ---- repack P^T -> PV B-frags via ds_bpermute ----
        union BF { int i[4]; f16x8 h; } bf0, bf1;
        #pragma unroll
        for (int s = 0; s < 2; ++s) {
            union BF* bf = s ? &bf1 : &bf0;
            const int rA = 2 * s, rB = 2 * s + 1;
            int a0 = __builtin_amdgcn_ds_bpermute(idx0, pk[rA][0]);
            int b0 = __builtin_amdgcn_ds_bpermute(idx0, pk[rB][0]);
            int a1 = __builtin_amdgcn_ds_bpermute(idx0, pk[rA][1]);
            int b1 = __builtin_amdgcn_ds_bpermute(idx0, pk[rB][1]);
            int a2 = __builtin_amdgcn_ds_bpermute(idx1, pk[rA][0]);
            int b2 = __builtin_amdgcn_ds_bpermute(idx1, pk[rB][0]);
            int a3 = __builtin_amdgcn_ds_bpermute(idx1, pk[rA][1]);
            int b3 = __builtin_amdgcn_ds_bpermute(idx1, pk[rB][1]);
            bf->i[0] = ghi ? b0 : a0;
            bf->i[1] = ghi ? b1 : a1;
            bf->i[2] = ghi ? b2 : a2;
            bf->i[3] = ghi ? b3 : a3;
        }

        // ---- O^T += Vt . P^T ----
        {
            const char* Vb = (const char*)Vbuf[cur];
            #pragma unroll
            for (int mm = 0; mm < 4; ++mm) {
                const char* rb = Vb + ((mm * 16 + fr) << 7);
                f16x8 va = *reinterpret_cast<const f16x8*>(rb + cs0);
                f16x8 vb = *reinterpret_cast<const f16x8*>(rb + cs1);
                o[mm] = __builtin_amdgcn_mfma_f32_16x16x32_f16(va, bf0.h, o[mm], 0, 0, 0);
                o[mm] = __builtin_amdgcn_mfma_f32_16x16x32_f16(vb, bf1.h, o[mm], 0, 0, 0);
            }
        }

        __syncthreads();
        cur ^= 1;
    }
#undef STAGE

    const float linv = 1.0f / l;
    const int b = bh >> 4, h = bh & 15;
    _Float16* Op = O + (size_t)(b * 2048 + qt * 64 + w * 16 + fr) * DIM
                     + h * 64 + 4 * g;
    #pragma unroll
    for (int mm = 0; mm < 4; ++mm) {
        f16x4 st;
        #pragma unroll
        for (int j = 0; j < 4; ++j) st[j] = (_Float16)(o[mm][j] * linv);
        *reinterpret_cast<f16x4*>(Op + mm * 16) = st;
    }
}

// ---------------------------------------------------------------------------
extern "C" void kernel_launch(void* const* d_in, const int* in_sizes, int n_in,
                              void* d_out, int out_size, void* d_ws, size_t ws_size,
                              hipStream_t stream)
{
    const float* x   = (const float*)d_in[0];
    const float* wq  = (const float*)d_in[1];
    const float* bq  = (const float*)d_in[2];
    const float* wk  = (const float*)d_in[3];
    const float* bk  = (const float*)d_in[4];
    const float* wv  = (const float*)d_in[5];
    const float* bv  = (const float*)d_in[6];
    const float* wo  = (const float*)d_in[7];
    const float* bo  = (const float*)d_in[8];
    const float* w1  = (const float*)d_in[9];
    const float* b1  = (const float*)d_in[10];
    const float* w2  = (const float*)d_in[11];
    const float* b2  = (const float*)d_in[12];
    const float* g1  = (const float*)d_in[13];
    const float* be1 = (const float*)d_in[14];
    const float* g2  = (const float*)d_in[15];
    const float* be2 = (const float*)d_in[16];
    float* out = (float*)d_out;

    // ws layout (peak 48MB + 12KB):
    //  [0,8M)   Wt      f16 transposed weights (per-GEMM)
    //  [8,16M)  normed  f16 [4096][1024]
    //  [16,24M) Qh      f16 [32][2048][64]   \
    //  [24,32M) Kh      f16 [32][2048][64]    } mid f16 [4096][4096] reuses
    //  [32,40M) Vt      f16 [32][64][2048]    } [16M,48M) after attention
    //  [40,48M) attno   f16 [4096][1024]     /
    //  [48M,+12K) bqkv  f32 [3072]
    char* wsb = (char*)d_ws;
    _Float16* Wt     = (_Float16*)(wsb);
    _Float16* normed = (_Float16*)(wsb + ((size_t)8  << 20));
    _Float16* Qh     = (_Float16*)(wsb + ((size_t)16 << 20));
    _Float16* Kh     = (_Float16*)(wsb + ((size_t)24 << 20));
    _Float16* Vt     = (_Float16*)(wsb + ((size_t)32 << 20));
    _Float16* mid    = (_Float16*)(wsb + ((size_t)16 << 20));
    _Float16* attno  = (_Float16*)(wsb + ((size_t)40 << 20));
    float*    bqkv   = (float*)   (wsb + ((size_t)48 << 20));

    // 1. LN1
    ln_kernel<<<MROWS, 256, 0, stream>>>(x, g1, be1, normed);
    // 2. fused QKV -> scattered f16 Q/K/Vt layouts
    concat3<<<12, 256, 0, stream>>>(bq, bk, bv, bqkv);
    transpose_cvt3<<<dim3(32, 32, 3), 256, 0, stream>>>(wq, wk, wv, Wt);
    gemm_mfma<3, 128><<<dim3(QKVS / 128, MROWS / 128), 256, 0, stream>>>(
        normed, Wt, bqkv, nullptr, nullptr, nullptr, Qh, Kh, Vt,
        MROWS, QKVS, DIM);
    // 3. MFMA flash attention
    attn_mfma<<<1024, 256, 0, stream>>>(Qh, Kh, Vt, attno);
    // 4. x2 = x + attno @ wo + bo -> d_out (f32)
    transpose_cvt<<<dim3(32, 32), 256, 0, stream>>>(wo, Wt, 1024, 1024, 0);
    gemm_mfma<1, 64><<<dim3(DIM / 128, MROWS / 64), 256, 0, stream>>>(
        attno, Wt, bo, x, out, nullptr, nullptr, nullptr, nullptr,
        MROWS, DIM, DIM);
    // 5. LN2
    ln_kernel<<<MROWS, 256, 0, stream>>>(out, g2, be2, normed);
    // 6. mid = gelu(h @ w1 + b1)  (f16, bounced stores)
    transpose_cvt<<<dim3(128, 32), 256, 0, stream>>>(w1, Wt, 1024, 4096, 0);
    gemm_mfma<2, 128><<<dim3(FFDIM / 128, MROWS / 128), 256, 0, stream>>>(
        normed, Wt, b1, nullptr, nullptr, mid, nullptr, nullptr, nullptr,
        MROWS, FFDIM, DIM);
    // 7. out = x2 + mid @ w2 + b2  (in-place residual, same-thread RMW)
    transpose_cvt<<<dim3(32, 128), 256, 0, stream>>>(w2, Wt, 4096, 1024, 0);
    gemm_mfma<1, 64><<<dim3(DIM / 128, MROWS / 64), 256, 0, stream>>>(
        mid, Wt, b2, out, out, nullptr, nullptr, nullptr, nullptr,
        MROWS, DIM, FFDIM);
}

// Round 10
// 454.112 us; speedup vs baseline: 2.5200x; 1.0070x over previous
//
#include <hip/hip_runtime.h>
#include <math.h>

#define DIM   1024
#define HEADS 16
#define HDIM  64
#define FFDIM 4096
#define MROWS 4096   // B*T = 2*2048
#define SEQ   2048
#define QKVS  3072   // fused q|k|v width
#define SCALE_Q 0.125f   // 1/sqrt(64); softmax in natural-log domain (__expf)

typedef _Float16 f16x8 __attribute__((ext_vector_type(8)));
typedef _Float16 f16x4 __attribute__((ext_vector_type(4)));
typedef float    f32x4 __attribute__((ext_vector_type(4)));

#define GLOAD_LDS16(g, l) __builtin_amdgcn_global_load_lds(                 \
    (const __attribute__((address_space(1))) void*)(g),                     \
    (__attribute__((address_space(3))) void*)(l), 16, 0, 0)

__device__ __forceinline__ float gelu_exact(float x) {
    return 0.5f * x * (1.0f + erff(x * 0.70710678118654752f));
}

// pack two f32 -> one dword of 2 f16 (scalar casts; known-good on gfx950)
__device__ __forceinline__ int pk2(float a, float b) {
    union { _Float16 h[2]; int i; } u;
    u.h[0] = (_Float16)a; u.h[1] = (_Float16)b;
    return u.i;
}

// ---------------------------------------------------------------------------
// LayerNorm: one 256-thread block per row of 1024 floats. fp16 output.
// ---------------------------------------------------------------------------
__device__ __forceinline__ void ln_row(
    const float* __restrict__ x, const float* __restrict__ g,
    const float* __restrict__ b, _Float16* __restrict__ out,
    int row, int t, float* red)
{
    const float4* xr = reinterpret_cast<const float4*>(x + (size_t)row * DIM);
    float4 v = xr[t];
    float s  = v.x + v.y + v.z + v.w;
    float ss = v.x*v.x + v.y*v.y + v.z*v.z + v.w*v.w;
    #pragma unroll
    for (int off = 32; off; off >>= 1) {
        s  += __shfl_down(s,  off);
        ss += __shfl_down(ss, off);
    }
    const int wave = t >> 6, lane = t & 63;
    if (lane == 0) { red[wave] = s; red[4 + wave] = ss; }
    __syncthreads();
    if (t == 0) {
        float S  = red[0] + red[1] + red[2] + red[3];
        float SS = red[4] + red[5] + red[6] + red[7];
        float mu  = S * (1.0f / DIM);
        float var = SS * (1.0f / DIM) - mu * mu;
        red[0] = mu;
        red[1] = rsqrtf(var + 1e-5f);
    }
    __syncthreads();
    const float mu = red[0], inv = red[1];
    const float4 gv = reinterpret_cast<const float4*>(g)[t];
    const float4 bv = reinterpret_cast<const float4*>(b)[t];
    f16x4 o;
    o[0] = (_Float16)((v.x - mu) * inv * gv.x + bv.x);
    o[1] = (_Float16)((v.y - mu) * inv * gv.y + bv.y);
    o[2] = (_Float16)((v.z - mu) * inv * gv.z + bv.z);
    o[3] = (_Float16)((v.w - mu) * inv * gv.w + bv.w);
    *reinterpret_cast<f16x4*>(out + (size_t)row * DIM + t * 4) = o;
}

__global__ __launch_bounds__(256) void ln_kernel(
    const float* __restrict__ x, const float* __restrict__ g,
    const float* __restrict__ b, _Float16* __restrict__ out)
{
    __shared__ float red[8];
    ln_row(x, g, b, out, blockIdx.x, threadIdx.x, red);
}

// ---------------------------------------------------------------------------
// prep1: fused LN1 (blocks 0..4095) + bias concat (4096..4107) +
// wq/wk/wv/wo transpose+cvt into Wt rows {0,1024,2048,3072} (4108..8203).
// ---------------------------------------------------------------------------
__global__ __launch_bounds__(256) void prep1(
    const float* __restrict__ x, const float* __restrict__ g1,
    const float* __restrict__ be1, _Float16* __restrict__ normed,
    const float* __restrict__ bq, const float* __restrict__ bk,
    const float* __restrict__ bv, float* __restrict__ bqkv,
    const float* __restrict__ wq, const float* __restrict__ wk,
    const float* __restrict__ wv, const float* __restrict__ wo,
    _Float16* __restrict__ Wt)
{
    __shared__ float smem[32 * 33];
    const int bid = blockIdx.x;
    const int tid = threadIdx.x;
    if (bid < 4096) {
        ln_row(x, g1, be1, normed, bid, tid, smem);
    } else if (bid < 4108) {
        const int i = (bid - 4096) * 256 + tid;   // 0..3071
        if (i < 1024)      bqkv[i] = bq[i];
        else if (i < 2048) bqkv[i] = bk[i - 1024];
        else               bqkv[i] = bv[i - 2048];
    } else {
        const int tb    = bid - 4108;
        const int which = tb >> 10;               // 0..3
        const int t32   = tb & 1023;
        const float* src = which == 0 ? wq : which == 1 ? wk
                         : which == 2 ? wv : wo;
        const int dstOff = which << 10;
        const int c0 = (t32 & 31) * 32, r0 = (t32 >> 5) * 32;
        const int tx = tid & 31, ty = (tid >> 5) * 4;
        float (*t)[33] = reinterpret_cast<float (*)[33]>(smem);
        #pragma unroll
        for (int i = 0; i < 4; ++i)
            t[ty + i][tx] = src[(size_t)(r0 + ty + i) * 1024 + c0 + tx];
        __syncthreads();
        #pragma unroll
        for (int i = 0; i < 4; ++i)
            Wt[(size_t)(dstOff + c0 + ty + i) * 1024 + r0 + tx] =
                (_Float16)t[tx][ty + i];
    }
}

// ---------------------------------------------------------------------------
// Transpose + fp32->fp16: src[R][C] f32 -> dst[c][r] f16 (for w1, w2)
// ---------------------------------------------------------------------------
__global__ __launch_bounds__(256) void transpose_cvt(
    const float* __restrict__ src, _Float16* __restrict__ dst,
    int R, int C)
{
    __shared__ float t[32][33];
    const int c0 = blockIdx.x * 32, r0 = blockIdx.y * 32;
    const int tx = threadIdx.x & 31, ty = (threadIdx.x >> 5) * 4;
    #pragma unroll
    for (int i = 0; i < 4; ++i)
        t[ty + i][tx] = src[(size_t)(r0 + ty + i) * C + c0 + tx];
    __syncthreads();
    #pragma unroll
    for (int i = 0; i < 4; ++i)
        dst[(size_t)(c0 + ty + i) * R + r0 + tx] = (_Float16)t[tx][ty + i];
}

// ---------------------------------------------------------------------------
// fp16 MFMA GEMM (m97 structure): C = epi(A[M,K] @ Bt[N,K]^T + bias),
// 128x128 tile, BK=32, 4 waves (2x2), mfma_f32_16x16x32_f16, f32 accum.
// EPI 1: +bias+res -> f32 (direct store)
// EPI 2: gelu(+bias) -> f16 row-major (LDS-bounce coalesced store)
// EPI 3: QKV scatter via LDS-bounce: q*SCALE_Q -> Qh[bh][t][64],
//        k -> Kh[bh][t][64], v -> Vt[bh][64][T]
// ---------------------------------------------------------------------------
template<int EPI>
__global__ __launch_bounds__(256) void gemm_mfma(
    const _Float16* __restrict__ A,   // [M][K]
    const _Float16* __restrict__ Bt,  // [N][K]
    const float* __restrict__ bias,   // [N]
    const float* __restrict__ res,    // [M][N] (EPI 1)
    float* __restrict__ Cf,           // f32 out (EPI 1)
    _Float16* __restrict__ Ch,        // f16 out (EPI 2)
    _Float16* __restrict__ Qh, _Float16* __restrict__ Kh,
    _Float16* __restrict__ Vtp,       // EPI 3 targets
    int M, int N, int K)
{
    __shared__ __attribute__((aligned(16))) _Float16 SMEM[8192];  // 16 KB
    _Float16* As = SMEM;             // 128*32
    _Float16* Bs = SMEM + 4096;      // 128*32

    const int tid  = threadIdx.x;
    const int wave = tid >> 6;
    const int lane = tid & 63;
    const int bm = blockIdx.y * 128;
    const int bn = blockIdx.x * 128;
    const int wr = wave >> 1, wc = wave & 1;

    const int c0   = wave * 2;
    const int srow = lane >> 2;
    const int skc  = lane & 3;
    const _Float16* Ag = A  + (size_t)(bm + c0 * 16 + srow) * K + skc * 8;
    const _Float16* Bg = Bt + (size_t)(bn + c0 * 16 + srow) * K + skc * 8;
    _Float16* Al = As + c0 * 512;
    _Float16* Bl = Bs + c0 * 512;

    f32x4 acc[4][4] = {};

    const int fr = lane & 15;
    const int fk = (lane >> 4) * 8;

    for (int k0 = 0; k0 < K; k0 += 32) {
        __syncthreads();
        GLOAD_LDS16(Ag + k0,                  Al);
        GLOAD_LDS16(Ag + k0 + 16 * (size_t)K, Al + 512);
        GLOAD_LDS16(Bg + k0,                  Bl);
        GLOAD_LDS16(Bg + k0 + 16 * (size_t)K, Bl + 512);
        __syncthreads();

        f16x8 af[4], bfr[4];
        #pragma unroll
        for (int m = 0; m < 4; ++m)
            af[m] = *reinterpret_cast<const f16x8*>(As + (wr * 64 + m * 16 + fr) * 32 + fk);
        #pragma unroll
        for (int n = 0; n < 4; ++n)
            bfr[n] = *reinterpret_cast<const f16x8*>(Bs + (wc * 64 + n * 16 + fr) * 32 + fk);
        #pragma unroll
        for (int m = 0; m < 4; ++m)
            #pragma unroll
            for (int n = 0; n < 4; ++n)
                acc[m][n] = __builtin_amdgcn_mfma_f32_16x16x32_f16(
                    af[m], bfr[n], acc[m][n], 0, 0, 0);
    }

    // C/D frag: col = lane&15 (=fr), row = (lane>>4)*4 + j
    const int fg = lane >> 4;

    if constexpr (EPI == 1) {
        #pragma unroll
        for (int m = 0; m < 4; ++m) {
            const int row0 = bm + wr * 64 + m * 16 + fg * 4;
            #pragma unroll
            for (int n = 0; n < 4; ++n) {
                const int col = bn + wc * 64 + n * 16 + fr;
                const float bv = bias[col];
                #pragma unroll
                for (int j = 0; j < 4; ++j) {
                    const size_t idx = (size_t)(row0 + j) * N + col;
                    Cf[idx] = acc[m][n][j] + bv + res[idx];
                }
            }
        }
        return;
    }

    // ---- LDS-bounce epilogue (EPI 2, 3): per-wave 32x64 f16 tiles ----
    _Float16* wtile = SMEM + wave * 2048;

    const int sect = bn >> 10;                       // 0=q 1=k 2=v
    const int bidx = bm >> 11;                       // batch
    const int t0w  = (bm & 2047) + wr * 64;          // wave's t base
    const int hh   = ((bn & 1023) >> 6) + wc;
    const size_t bh = (size_t)(bidx * 16 + hh);

    #pragma unroll
    for (int pass = 0; pass < 2; ++pass) {
        __syncthreads();
        #pragma unroll
        for (int mi = 0; mi < 2; ++mi) {
            const int mm = pass * 2 + mi;
            #pragma unroll
            for (int n = 0; n < 4; ++n) {
                const int cl = n * 16 + fr;
                const float bv = bias[bn + wc * 64 + cl];
                #pragma unroll
                for (int j = 0; j < 4; ++j) {
                    const int rl = mi * 16 + fg * 4 + j;
                    float v = acc[mm][n][j] + bv;
                    _Float16 hv;
                    if constexpr (EPI == 2) hv = (_Float16)gelu_exact(v);
                    else hv = (_Float16)(sect == 0 ? v * SCALE_Q : v);
                    wtile[rl * 64 + ((((cl >> 3) ^ (rl & 7))) << 3) + (cl & 7)] = hv;
                }
            }
        }
        __syncthreads();

        if constexpr (EPI == 2) {
            _Float16* dst = Ch + (size_t)(bm + wr * 64 + pass * 32) * N
                               + bn + wc * 64;
            #pragma unroll
            for (int it = 0; it < 4; ++it) {
                const int rl = it * 8 + (lane >> 3);
                const int ch = lane & 7;
                f16x8 vv = *reinterpret_cast<const f16x8*>(
                    wtile + rl * 64 + ((ch ^ (rl & 7)) << 3));
                *reinterpret_cast<f16x8*>(dst + (size_t)rl * N + ch * 8) = vv;
            }
        } else {  // EPI == 3
            if (sect < 2) {
                _Float16* dst = (sect == 0 ? Qh : Kh)
                              + (bh * 2048 + t0w + pass * 32) * 64;
                #pragma unroll
                for (int it = 0; it < 4; ++it) {
                    const int rl = it * 8 + (lane >> 3);
                    const int ch = lane & 7;
                    f16x8 vv = *reinterpret_cast<const f16x8*>(
                        wtile + rl * 64 + ((ch ^ (rl & 7)) << 3));
                    *reinterpret_cast<f16x8*>(dst + (size_t)rl * 64 + ch * 8) = vv;
                }
            } else {
                // V: transposed read (column d, 8 t's) -> Vt[bh][d][T]
                _Float16* dst = Vtp + bh * (64 * 2048) + t0w + pass * 32;
                #pragma unroll
                for (int it = 0; it < 4; ++it) {
                    const int d   = it * 16 + (lane >> 2);
                    const int tch = lane & 3;
                    f16x8 vv;
                    #pragma unroll
                    for (int u = 0; u < 8; ++u) {
                        const int rl = tch * 8 + u;
                        vv[u] = wtile[rl * 64 + (((d >> 3) ^ (rl & 7)) << 3) + (d & 7)];
                    }
                    *reinterpret_cast<f16x8*>(dst + (size_t)d * 2048 + tch * 8) = vv;
                }
            }
        }
    }
}

// ---------------------------------------------------------------------------
// MFMA flash attention. Qh [bh][T][64] (pre-scaled by 0.125), Kh [bh][T][64],
// Vt [bh][64][T]. Softmax via __expf (native v_exp). T13 defer-max.
// ---------------------------------------------------------------------------
__global__ __launch_bounds__(256) void attn_mfma(
    const _Float16* __restrict__ Qh, const _Float16* __restrict__ Kh,
    const _Float16* __restrict__ Vt, _Float16* __restrict__ O)
{
    __shared__ __attribute__((aligned(16))) _Float16 Kbuf[2][4096];
    __shared__ __attribute__((aligned(16))) _Float16 Vbuf[2][4096];

    const int fid = blockIdx.x;
    const int qt  = (fid >> 3) & 31;
    const int bh  = (fid & 7) * 4 + (fid >> 8);

    const int tid  = threadIdx.x;
    const int w    = tid >> 6;
    const int lane = tid & 63;
    const int fr   = lane & 15;
    const int g    = lane >> 4;

    const int srow_lo = lane >> 3;
    const int sc      = (lane & 7) ^ (srow_lo & 7);
    const int rowA = w * 8 + srow_lo;
    const int rowB = (w + 4) * 8 + srow_lo;
    const char* Kg = (const char*)(Kh + (size_t)bh * (2048 * 64));
    const char* Vg = (const char*)(Vt + (size_t)bh * (64 * 2048));

#define STAGE(nb, kt) do {                                                   \
    GLOAD_LDS16(Kg + ((size_t)(((kt) * 64 + rowA)) << 7) + (sc << 4),        \
                &Kbuf[nb][w * 512]);                                         \
    GLOAD_LDS16(Kg + ((size_t)(((kt) * 64 + rowB)) << 7) + (sc << 4),        \
                &Kbuf[nb][(w + 4) * 512]);                                   \
    GLOAD_LDS16(Vg + ((size_t)rowA << 12) + ((kt) << 7) + (sc << 4),         \
                &Vbuf[nb][w * 512]);                                         \
    GLOAD_LDS16(Vg + ((size_t)rowB << 12) + ((kt) << 7) + (sc << 4),         \
                &Vbuf[nb][(w + 4) * 512]);                                   \
} while (0)

    const int qrow = qt * 64 + w * 16 + fr;
    const f16x8* Qp = reinterpret_cast<const f16x8*>(
        Qh + ((size_t)bh * 2048 + qrow) * 64);
    const f16x8 qf0 = Qp[g];
    const f16x8 qf1 = Qp[4 + g];

    const int fr7 = fr & 7;
    const int cs0 = ((g ^ fr7) << 4);
    const int cs1 = (((4 + g) ^ fr7) << 4);

    f32x4 o[4] = {};
    float mrun = -INFINITY, l = 0.0f;

    const int idx0 = (fr + ((g & 1) << 5)) << 2;
    const int idx1 = idx0 + 64;
    const bool ghi = (g >= 2);

    STAGE(0, 0);
    __syncthreads();
    int cur = 0;

    for (int kt = 0; kt < 32; ++kt) {
        if (kt < 31) STAGE(cur ^ 1, kt + 1);

        // ---- S^T = K . Q^T ----
        f32x4 sT[4] = {};
        {
            const char* Kb = (const char*)Kbuf[cur];
            #pragma unroll
            for (int mm = 0; mm < 4; ++mm) {
                const char* rb = Kb + ((mm * 16 + fr) << 7);
                f16x8 ka = *reinterpret_cast<const f16x8*>(rb + cs0);
                f16x8 kb = *reinterpret_cast<const f16x8*>(rb + cs1);
                sT[mm] = __builtin_amdgcn_mfma_f32_16x16x32_f16(ka, qf0, sT[mm], 0, 0, 0);
                sT[mm] = __builtin_amdgcn_mfma_f32_16x16x32_f16(kb, qf1, sT[mm], 0, 0, 0);
            }
        }

        // ---- online softmax (natural-log domain, native exp) ----
        float pm = sT[0][0];
        #pragma unroll
        for (int mm = 0; mm < 4; ++mm)
            #pragma unroll
            for (int j = 0; j < 4; ++j) pm = fmaxf(pm, sT[mm][j]);
        pm = fmaxf(pm, __shfl_xor(pm, 16));
        pm = fmaxf(pm, __shfl_xor(pm, 32));
        if (!__all(pm - mrun <= 8.0f)) {
            const float mnew  = fmaxf(mrun, pm);
            const float alpha = __expf(mrun - mnew);
            mrun = mnew;
            l *= alpha;
            #pragma unroll
            for (int mm = 0; mm < 4; ++mm)
                #pragma unroll
                for (int j = 0; j < 4; ++j) o[mm][j] *= alpha;
        }
        float rs = 0.0f;
        #pragma unroll
        for (int mm = 0; mm < 4; ++mm)
            #pragma unroll
            for (int j = 0; j < 4; ++j) {
                const float p = __expf(sT[mm][j] - mrun);
                sT[mm][j] = p;
                rs += p;
            }
        rs += __shfl_xor(rs, 16);
        rs += __shfl_xor(rs, 32);
        l += rs;

        // ---- pack P to f16 pairs ----
        int pk[4][2];
        #pragma unroll
        for (int mm = 0; mm < 4; ++mm) {
            pk[mm][0] = pk2(sT[mm][0], sT[mm][1]);
            pk[mm][1] = pk2(sT[mm][2], sT[mm][3]);
        }

        // ---- repack P^T -> PV B-frags via ds_bpermute ----
        union BF { int i[4]; f16x8 h; } bf0, bf1;
        #pragma unroll
        for (int s = 0; s < 2; ++s) {
            union BF* bf = s ? &bf1 : &bf0;
            const int rA = 2 * s, rB = 2 * s + 1;
            int a0 = __builtin_amdgcn_ds_bpermute(idx0, pk[rA][0]);
            int b0 = __builtin_amdgcn_ds_bpermute(idx0, pk[rB][0]);
            int a1 = __builtin_amdgcn_ds_bpermute(idx0, pk[rA][1]);
            int b1 = __builtin_amdgcn_ds_bpermute(idx0, pk[rB][1]);
            int a2 = __builtin_amdgcn_ds_bpermute(idx1, pk[rA][0]);
            int b2 = __builtin_amdgcn_ds_bpermute(idx1, pk[rB][0]);
            int a3 = __builtin_amdgcn_ds_bpermute(idx1, pk[rA][1]);
            int b3 = __builtin_amdgcn_ds_bpermute(idx1, pk[rB][1]);
            bf->i[0] = ghi ? b0 : a0;
            bf->i[1] = ghi ? b1 : a1;
            bf->i[2] = ghi ? b2 : a2;
            bf->i[3] = ghi ? b3 : a3;
        }

        // ---- O^T += Vt . P^T ----
        {
            const char* Vb = (const char*)Vbuf[cur];
            #pragma unroll
            for (int mm = 0; mm < 4; ++mm) {
                const char* rb = Vb + ((mm * 16 + fr) << 7);
                f16x8 va = *reinterpret_cast<const f16x8*>(rb + cs0);
                f16x8 vb = *reinterpret_cast<const f16x8*>(rb + cs1);
                o[mm] = __builtin_amdgcn_mfma_f32_16x16x32_f16(va, bf0.h, o[mm], 0, 0, 0);
                o[mm] = __builtin_amdgcn_mfma_f32_16x16x32_f16(vb, bf1.h, o[mm], 0, 0, 0);
            }
        }

        __syncthreads();
        cur ^= 1;
    }
#undef STAGE

    const float linv = 1.0f / l;
    const int b = bh >> 4, h = bh & 15;
    _Float16* Op = O + (size_t)(b * 2048 + qt * 64 + w * 16 + fr) * DIM
                     + h * 64 + 4 * g;
    #pragma unroll
    for (int mm = 0; mm < 4; ++mm) {
        f16x4 st;
        #pragma unroll
        for (int j = 0; j < 4; ++j) st[j] = (_Float16)(o[mm][j] * linv);
        *reinterpret_cast<f16x4*>(Op + mm * 16) = st;
    }
}

// ---------------------------------------------------------------------------
extern "C" void kernel_launch(void* const* d_in, const int* in_sizes, int n_in,
                              void* d_out, int out_size, void* d_ws, size_t ws_size,
                              hipStream_t stream)
{
    const float* x   = (const float*)d_in[0];
    const float* wq  = (const float*)d_in[1];
    const float* bq  = (const float*)d_in[2];
    const float* wk  = (const float*)d_in[3];
    const float* bk  = (const float*)d_in[4];
    const float* wv  = (const float*)d_in[5];
    const float* bv  = (const float*)d_in[6];
    const float* wo  = (const float*)d_in[7];
    const float* bo  = (const float*)d_in[8];
    const float* w1  = (const float*)d_in[9];
    const float* b1  = (const float*)d_in[10];
    const float* w2  = (const float*)d_in[11];
    const float* b2  = (const float*)d_in[12];
    const float* g1  = (const float*)d_in[13];
    const float* be1 = (const float*)d_in[14];
    const float* g2  = (const float*)d_in[15];
    const float* be2 = (const float*)d_in[16];
    float* out = (float*)d_out;

    // ws layout (peak 48MB + 12KB):
    //  [0,8M)   Wt      f16: wq^T|wk^T|wv^T|wo^T rows 0/1024/2048/3072;
    //                   later reused for w1^T then w2^T
    //  [8,16M)  normed  f16 [4096][1024]
    //  [16,24M) Qh      f16 [32][2048][64]   \
    //  [24,32M) Kh      f16 [32][2048][64]    } mid f16 [4096][4096] reuses
    //  [32,40M) Vt      f16 [32][64][2048]    } [16M,48M) after attention
    //  [40,48M) attno   f16 [4096][1024]     /
    //  [48M,+12K) bqkv  f32 [3072]
    char* wsb = (char*)d_ws;
    _Float16* Wt     = (_Float16*)(wsb);
    _Float16* normed = (_Float16*)(wsb + ((size_t)8  << 20));
    _Float16* Qh     = (_Float16*)(wsb + ((size_t)16 << 20));
    _Float16* Kh     = (_Float16*)(wsb + ((size_t)24 << 20));
    _Float16* Vt     = (_Float16*)(wsb + ((size_t)32 << 20));
    _Float16* mid    = (_Float16*)(wsb + ((size_t)16 << 20));
    _Float16* attno  = (_Float16*)(wsb + ((size_t)40 << 20));
    float*    bqkv   = (float*)   (wsb + ((size_t)48 << 20));

    // 1. prep: LN1 + bias concat + wq/wk/wv/wo transposes
    prep1<<<8204, 256, 0, stream>>>(x, g1, be1, normed, bq, bk, bv, bqkv,
                                    wq, wk, wv, wo, Wt);
    // 2. fused QKV GEMM -> scattered f16 Q/K/Vt layouts
    gemm_mfma<3><<<dim3(QKVS / 128, MROWS / 128), 256, 0, stream>>>(
        normed, Wt, bqkv, nullptr, nullptr, nullptr, Qh, Kh, Vt,
        MROWS, QKVS, DIM);
    // 3. MFMA flash attention
    attn_mfma<<<1024, 256, 0, stream>>>(Qh, Kh, Vt, attno);
    // 4. x2 = x + attno @ wo + bo -> d_out (f32); wo^T at Wt row 3072
    gemm_mfma<1><<<dim3(DIM / 128, MROWS / 128), 256, 0, stream>>>(
        attno, Wt + (size_t)3072 * 1024, bo, x, out, nullptr,
        nullptr, nullptr, nullptr, MROWS, DIM, DIM);
    // 5. LN2
    ln_kernel<<<MROWS, 256, 0, stream>>>(out, g2, be2, normed);
    // 6. mid = gelu(h @ w1 + b1)  (f16, bounced stores)
    transpose_cvt<<<dim3(128, 32), 256, 0, stream>>>(w1, Wt, 1024, 4096);
    gemm_mfma<2><<<dim3(FFDIM / 128, MROWS / 128), 256, 0, stream>>>(
        normed, Wt, b1, nullptr, nullptr, mid, nullptr, nullptr, nullptr,
        MROWS, FFDIM, DIM);
    // 7. out = x2 + mid @ w2 + b2  (in-place residual, same-thread RMW)
    transpose_cvt<<<dim3(32, 128), 256, 0, stream>>>(w2, Wt, 4096, 1024);
    gemm_mfma<1><<<dim3(DIM / 128, MROWS / 128), 256, 0, stream>>>(
        mid, Wt, b2, out, out, nullptr, nullptr, nullptr, nullptr,
        MROWS, DIM, FFDIM);
}